// Round 2
// baseline (362.636 us; speedup 1.0000x reference)
//
#include <hip/hip_runtime.h>
#include <math.h>

#define SRC_LEN 2048
#define BATCH   32
#define EHID    1024   // 2*enc_hid_dim (inner dim of enc_outputs)
#define DHID    1024   // dec_hid_dim
#define NPAIRS  (SRC_LEN * BATCH)   // 65536 rows of 4 KB

// fast tanh via v_exp_f32: tanh(x) = (e^2x - 1)/(e^2x + 1)
__device__ __forceinline__ float fast_tanh(float x) {
    float a = __expf(2.0f * x);
    return (a - 1.0f) / (a + 1.0f);
}

// Kernel 1: dec_e[b] = dot(dec_hidden[b,:], W[0,0:DHID]) + bias
__global__ void dec_dot_kernel(const float* __restrict__ dec_hidden,
                               const float* __restrict__ W,
                               const float* __restrict__ bias,
                               float* __restrict__ dec_e) {
    const int b = blockIdx.x;
    const int t = threadIdx.x;
    const float4* dh = (const float4*)(dec_hidden + (size_t)b * DHID);
    const float4* w  = (const float4*)W;
    float4 a  = dh[t];
    float4 ww = w[t];
    float acc = a.x * ww.x + a.y * ww.y + a.z * ww.z + a.w * ww.w;
    #pragma unroll
    for (int off = 32; off > 0; off >>= 1)
        acc += __shfl_down(acc, off, 64);
    __shared__ float smem[4];
    const int wid  = t >> 6;
    const int lane = t & 63;
    if (lane == 0) smem[wid] = acc;
    __syncthreads();
    if (t == 0)
        dec_e[b] = smem[0] + smem[1] + smem[2] + smem[3] + bias[0];
}

// Kernel 2: persistent-style. 1024 blocks x 8 waves; each wave owns 8
// contiguous rows (pairs). w_enc slice lives in 16 VGPRs for the whole wave;
// 2-row unroll -> 8 independent dwordx4 HBM loads in flight.
__global__ __launch_bounds__(512) void score_kernel(
        const float* __restrict__ enc,    // [s][b][e], row = pair = s*32+b
        const float* __restrict__ W,      // w_enc at W+DHID
        const float* __restrict__ dec_e,  // [BATCH]
        float* __restrict__ out) {        // [b][s]
    const int lane = threadIdx.x & 63;
    const int wid  = threadIdx.x >> 6;              // 8 waves/block
    const int wave = blockIdx.x * 8 + wid;          // 8192 waves total
    const size_t base = (size_t)wave * 8;           // first pair of this wave

    // hoist w_enc slice into registers (one load per lane-slot, L2-resident)
    const float4* w4 = (const float4*)(W + DHID);
    float4 wr[4];
    #pragma unroll
    for (int j = 0; j < 4; ++j) wr[j] = w4[lane + 64 * j];

    #pragma unroll
    for (int i = 0; i < 8; i += 2) {
        const float4* r0 = (const float4*)enc + (base + i) * (EHID / 4);
        const float4* r1 = r0 + (EHID / 4);
        float acc0 = 0.0f, acc1 = 0.0f;
        #pragma unroll
        for (int j = 0; j < 4; ++j) {
            float4 a0 = r0[lane + 64 * j];
            float4 a1 = r1[lane + 64 * j];
            acc0 = fmaf(a0.x, wr[j].x, acc0);
            acc0 = fmaf(a0.y, wr[j].y, acc0);
            acc0 = fmaf(a0.z, wr[j].z, acc0);
            acc0 = fmaf(a0.w, wr[j].w, acc0);
            acc1 = fmaf(a1.x, wr[j].x, acc1);
            acc1 = fmaf(a1.y, wr[j].y, acc1);
            acc1 = fmaf(a1.z, wr[j].z, acc1);
            acc1 = fmaf(a1.w, wr[j].w, acc1);
        }
        // two independent butterfly chains interleave -> latency hidden
        #pragma unroll
        for (int off = 32; off > 0; off >>= 1) {
            acc0 += __shfl_down(acc0, off, 64);
            acc1 += __shfl_down(acc1, off, 64);
        }
        if (lane == 0) {
            const int p0 = (int)(base + i), p1 = p0 + 1;
            const int s0 = p0 >> 5, b0 = p0 & 31;
            const int s1 = p1 >> 5, b1 = p1 & 31;
            float e0 = dec_e[b0] + acc0;
            float e1 = dec_e[b1] + acc1;
            out[(size_t)b0 * SRC_LEN + s0] = __expf(fast_tanh(e0));
            out[(size_t)b1 * SRC_LEN + s1] = __expf(fast_tanh(e1));
        }
    }
}

// Kernel 3: per-row normalize. 32 blocks (one per batch) x 256 threads.
__global__ void softmax_norm_kernel(float* __restrict__ out) {
    const int b = blockIdx.x;
    const int t = threadIdx.x;
    float4* row = (float4*)(out + (size_t)b * SRC_LEN);  // 512 float4
    float4 v0 = row[t];
    float4 v1 = row[t + 256];
    float acc = v0.x + v0.y + v0.z + v0.w + v1.x + v1.y + v1.z + v1.w;
    #pragma unroll
    for (int off = 32; off > 0; off >>= 1)
        acc += __shfl_down(acc, off, 64);
    __shared__ float smem[4];
    const int wid  = t >> 6;
    const int lane = t & 63;
    if (lane == 0) smem[wid] = acc;
    __syncthreads();
    const float inv = 1.0f / (smem[0] + smem[1] + smem[2] + smem[3]);
    v0.x *= inv; v0.y *= inv; v0.z *= inv; v0.w *= inv;
    v1.x *= inv; v1.y *= inv; v1.z *= inv; v1.w *= inv;
    row[t]       = v0;
    row[t + 256] = v1;
}

extern "C" void kernel_launch(void* const* d_in, const int* in_sizes, int n_in,
                              void* d_out, int out_size, void* d_ws, size_t ws_size,
                              hipStream_t stream) {
    const float* dec_hidden = (const float*)d_in[0];  // (32, 1024)
    const float* enc        = (const float*)d_in[1];  // (2048, 32, 1024)
    const float* W          = (const float*)d_in[2];  // (1, 2048)
    const float* bias       = (const float*)d_in[3];  // (1,)
    float* out   = (float*)d_out;                     // (32, 2048)
    float* dec_e = (float*)d_ws;                      // 32 floats scratch

    dec_dot_kernel<<<BATCH, 256, 0, stream>>>(dec_hidden, W, bias, dec_e);
    score_kernel<<<NPAIRS / 64, 512, 0, stream>>>(enc, W, dec_e, out);
    softmax_norm_kernel<<<BATCH, 256, 0, stream>>>(out);
}